// Round 1
// 484.169 us; speedup vs baseline: 1.0266x; 1.0266x over previous
//
#include <hip/hip_runtime.h>

// Masked embedding lookup:
//   out[b,h,:] = (idx[b,h] == -1) ? 0 : table[idx[b,h], :]
// Shapes: idx [4096*200] int32, table [100000,128] f32, out [4096*200,128] f32.
//
// Strategy: 32 lanes cooperate on one 128-float (512 B) row; each lane moves
// one float4 (16 B) — reads and writes fully coalesced.
//
// Key change this round: NON-TEMPORAL output stores. The 419 MB output
// stream was write-allocating through L2/L3 and continuously evicting the
// 51 MB table, destroying the ~8x average row reuse (gather reads ballooned
// to ~419 MB of random HBM traffic). `nt` stores keep the table resident in
// the 256 MB Infinity Cache, so reads collapse to ~54 MB of cold misses.

#define EMB_DIM   128
#define NO_LABEL  (-1)
#define LANES_PER_ROW 32

typedef float __attribute__((ext_vector_type(4))) f32x4;

__global__ __launch_bounds__(256) void lookup_kernel(
    const int* __restrict__ idx,
    const float* __restrict__ table,
    float* __restrict__ out,
    int n_rows)
{
    const int gtid = blockIdx.x * blockDim.x + threadIdx.x;
    const int row  = gtid >> 5;        // 32 threads per row
    const int lane = gtid & 31;
    if (row >= n_rows) return;

    const int id = idx[row];           // broadcast within the 32-lane group

    f32x4 v = {0.f, 0.f, 0.f, 0.f};
    if (id != NO_LABEL) {
        const f32x4* __restrict__ src =
            (const f32x4*)(table + (size_t)id * EMB_DIM);
        v = src[lane];                 // cached read — table stays in L3
    }

    f32x4* dst = (f32x4*)(out + (size_t)row * EMB_DIM) + lane;
    __builtin_nontemporal_store(v, dst);   // streaming write, no cache allocate
}

extern "C" void kernel_launch(void* const* d_in, const int* in_sizes, int n_in,
                              void* d_out, int out_size, void* d_ws, size_t ws_size,
                              hipStream_t stream) {
    const int*   idx   = (const int*)d_in[0];    // input_batch, int32 per harness
    const float* table = (const float*)d_in[1];  // [100000,128] f32
    float*       out   = (float*)d_out;          // [B*H,128] f32

    const int n_rows = in_sizes[0];              // 4096*200 = 819200
    const int total_threads = n_rows * LANES_PER_ROW;
    const int block = 256;
    const int grid  = (total_threads + block - 1) / block;

    lookup_kernel<<<grid, block, 0, stream>>>(idx, table, out, n_rows);
}

// Round 2
// 468.416 us; speedup vs baseline: 1.0611x; 1.0336x over previous
//
#include <hip/hip_runtime.h>

// Masked embedding lookup:
//   out[b,h,:] = (idx[b,h] == -1) ? 0 : table[idx[b,h], :]
// Shapes: idx [4096*200] int32, table [100000,128] f32, out [4096*200,128] f32.
//
// Strategy this round: MLP. Each 32-lane group handles FOUR consecutive rows:
//   - one int4 load fetches all 4 indices (16 B broadcast),
//   - four INDEPENDENT 16 B gather loads issue back-to-back (4 outstanding
//     random reads per thread instead of 1 — hides the ~600-900 cyc
//     L3/HBM gather latency),
//   - four nt stores cover a contiguous 2 KB output region per group.
// Previous single-row version was latency-exposed: 1 dependent
// idx->gather->store chain per thread ran the memory system at 3.6 TB/s
// vs the 6.4 TB/s the pure-write fill achieves on the same machine.

#define EMB_DIM   128
#define NO_LABEL  (-1)
#define ROWS_PER_GROUP 4

typedef float __attribute__((ext_vector_type(4))) f32x4;

__global__ __launch_bounds__(256) void lookup_kernel(
    const int* __restrict__ idx,
    const float* __restrict__ table,
    float* __restrict__ out,
    int n_rows)
{
    const int gtid = blockIdx.x * blockDim.x + threadIdx.x;
    const int grp  = gtid >> 5;        // 32 lanes per group
    const int lane = gtid & 31;
    const int row0 = grp * ROWS_PER_GROUP;
    if (row0 >= n_rows) return;

    f32x4 v0 = {0.f,0.f,0.f,0.f}, v1 = v0, v2 = v0, v3 = v0;

    if (row0 + ROWS_PER_GROUP <= n_rows) {
        // fast path: one 16 B index load, 4 independent gathers
        const int4 ids = *(const int4*)(idx + row0);
        if (ids.x != NO_LABEL)
            v0 = ((const f32x4*)(table + (size_t)ids.x * EMB_DIM))[lane];
        if (ids.y != NO_LABEL)
            v1 = ((const f32x4*)(table + (size_t)ids.y * EMB_DIM))[lane];
        if (ids.z != NO_LABEL)
            v2 = ((const f32x4*)(table + (size_t)ids.z * EMB_DIM))[lane];
        if (ids.w != NO_LABEL)
            v3 = ((const f32x4*)(table + (size_t)ids.w * EMB_DIM))[lane];

        f32x4* dst = (f32x4*)(out + (size_t)row0 * EMB_DIM) + lane;
        __builtin_nontemporal_store(v0, dst);
        __builtin_nontemporal_store(v1, dst + 32);   // next row, same lane
        __builtin_nontemporal_store(v2, dst + 64);
        __builtin_nontemporal_store(v3, dst + 96);
    } else {
        // tail (not hit for 819200 rows, kept for generality)
        for (int r = row0; r < n_rows; ++r) {
            const int id = idx[r];
            f32x4 v = {0.f,0.f,0.f,0.f};
            if (id != NO_LABEL)
                v = ((const f32x4*)(table + (size_t)id * EMB_DIM))[lane];
            __builtin_nontemporal_store(v, (f32x4*)(out + (size_t)r * EMB_DIM) + lane);
        }
    }
}

extern "C" void kernel_launch(void* const* d_in, const int* in_sizes, int n_in,
                              void* d_out, int out_size, void* d_ws, size_t ws_size,
                              hipStream_t stream) {
    const int*   idx   = (const int*)d_in[0];    // input_batch, int32 per harness
    const float* table = (const float*)d_in[1];  // [100000,128] f32
    float*       out   = (float*)d_out;          // [B*H,128] f32

    const int n_rows  = in_sizes[0];             // 4096*200 = 819200
    const int n_grps  = (n_rows + ROWS_PER_GROUP - 1) / ROWS_PER_GROUP;
    const int total_threads = n_grps * 32;
    const int block = 256;
    const int grid  = (total_threads + block - 1) / block;

    lookup_kernel<<<grid, block, 0, stream>>>(idx, table, out, n_rows);
}